// Round 1
// baseline (1277.591 us; speedup 1.0000x reference)
//
#include <hip/hip_runtime.h>
#include <cmath>
#include <cstdint>

#define TSZ 1024
#define RDIV 2.5f
#define UCONST 0.83f

// ws layout (bytes):
// 0    : float norms2[256]
// 1024 : float scale
// 1088 : int bucket[256]
// 2112 : int count[1024]
// 6208 : int maskI[256]

__global__ __launch_bounds__(256) void k_sumsq(const float* __restrict__ k,
                                               float* __restrict__ norms2) {
  int o = blockIdx.x;
  const float* row = k + (size_t)o * 1152;
  float s = 0.f;
  for (int j = threadIdx.x; j < 1152; j += 256) { float v = row[j]; s += v * v; }
  __shared__ float red[256];
  red[threadIdx.x] = s; __syncthreads();
  for (int st = 128; st; st >>= 1) {
    if (threadIdx.x < st) red[threadIdx.x] += red[threadIdx.x + st];
    __syncthreads();
  }
  if (threadIdx.x == 0) norms2[o] = red[0];
}

__global__ __launch_bounds__(256) void k_scale(const float* __restrict__ norms2,
                                               float* __restrict__ scale) {
  __shared__ float red[256];
  red[threadIdx.x] = norms2[threadIdx.x]; __syncthreads();
  for (int st = 128; st; st >>= 1) {
    if (threadIdx.x < st) red[threadIdx.x] = fmaxf(red[threadIdx.x], red[threadIdx.x + st]);
    __syncthreads();
  }
  if (threadIdx.x == 0) scale[0] = UCONST / sqrtf(red[0]);
}

__global__ __launch_bounds__(256) void k_hash(const float* __restrict__ k,
                                              const float* __restrict__ a,
                                              const float* __restrict__ b,
                                              const float* __restrict__ scalep,
                                              int* __restrict__ bucket) {
  int o = blockIdx.x;
  float scale = scalep[0];
  const float* row = k + (size_t)o * 1152;
  float dot = 0.f, p = 0.f;
  for (int j = threadIdx.x; j < 1152; j += 256) {
    float x = row[j] * scale;
    dot += x * a[j];
    p += x * x;
  }
  __shared__ float rd[256], rp[256];
  rd[threadIdx.x] = dot; rp[threadIdx.x] = p; __syncthreads();
  for (int st = 128; st; st >>= 1) {
    if (threadIdx.x < st) { rd[threadIdx.x] += rd[threadIdx.x + st]; rp[threadIdx.x] += rp[threadIdx.x + st]; }
    __syncthreads();
  }
  if (threadIdx.x == 0) {
    float acc = rd[0];
    float pw = rp[0];
    // append powers p^(2^i), i = 0..8, times a[1152+i]
    for (int i = 0; i < 9; i++) { acc += pw * a[1152 + i]; pw = pw * pw; }
    acc += b[0];
    float h = floorf(acc / RDIV);
    int hi = (int)h;
    int r = hi % TSZ; if (r < 0) r = -r;  // fmod + abs semantics
    bucket[o] = r;
  }
}

__global__ __launch_bounds__(256) void k_vote(const float* __restrict__ in,
                                              const float* __restrict__ a,
                                              const float* __restrict__ b,
                                              int* __restrict__ count) {
  __shared__ int hist[TSZ];
  for (int i = threadIdx.x; i < TSZ; i += 256) hist[i] = 0;
  __syncthreads();

  int pix = blockIdx.x * 256 + threadIdx.x;     // 0..65535
  int x = pix & 63, y = (pix >> 6) & 63, n = pix >> 12;
  const float* base = in + (size_t)n * 128 * 4096;
  float acc = 0.f;
  for (int c = 0; c < 128; c++) {
    const float* ch = base + (size_t)c * 4096;
    const float* av = a + c * 9;
#pragma unroll
    for (int ky = 0; ky < 3; ky++) {
      int yy = y + ky - 1;
      if ((unsigned)yy >= 64u) continue;
      const float* rowp = ch + yy * 64;
#pragma unroll
      for (int kx = 0; kx < 3; kx++) {
        int xx = x + kx - 1;
        if ((unsigned)xx >= 64u) continue;
        acc += rowp[xx] * av[ky * 3 + kx];
      }
    }
  }
  // appended constant-0.5 channel (zero-padded like everything else)
  {
    const float* av = a + 1152;
#pragma unroll
    for (int ky = 0; ky < 3; ky++) {
      int yy = y + ky - 1;
      if ((unsigned)yy >= 64u) continue;
#pragma unroll
      for (int kx = 0; kx < 3; kx++) {
        int xx = x + kx - 1;
        if ((unsigned)xx >= 64u) continue;
        acc += 0.5f * av[ky * 3 + kx];
      }
    }
  }
  int v = (int)floorf((acc + b[0]) / RDIV);
  int r = v % TSZ; if (r < 0) r = -r;
  atomicAdd(&hist[r], 1);
  __syncthreads();
  for (int i = threadIdx.x; i < TSZ; i += 256) {
    int h = hist[i];
    if (h) atomicAdd(&count[i], h);
  }
}

__global__ __launch_bounds__(1024) void k_argmax(const int* __restrict__ count,
                                                 const int* __restrict__ bucket,
                                                 int* __restrict__ maskI,
                                                 float* __restrict__ tail) {
  __shared__ int sc[1024];
  __shared__ int si[1024];
  int t = threadIdx.x;
  sc[t] = count[t]; si[t] = t; __syncthreads();
  for (int st = 512; st; st >>= 1) {
    if (t < st) {
      int c2 = sc[t + st], i2 = si[t + st];
      if (c2 > sc[t] || (c2 == sc[t] && i2 < si[t])) { sc[t] = c2; si[t] = i2; }
    }
    __syncthreads();
  }
  int idx = si[0];
  if (t == 0) tail[0] = (float)idx;
  if (t < 256) {
    int m = (bucket[t] == idx) ? 1 : 0;
    maskI[t] = m;
    tail[1 + t] = (float)m;
  }
}

// Direct fp32 conv: block = 256 thr = 64 cols x 4 rows; 4 output channels/block.
// grid: x = oc-group (64), y = batch (16), z = y-tile (16) -> og fastest for L2 reuse of input.
__global__ __launch_bounds__(256) void k_conv(const float* __restrict__ in,
                                              const float* __restrict__ w,
                                              const int* __restrict__ maskI,
                                              float* __restrict__ out) {
  const int og = blockIdx.x, n = blockIdx.y, yt = blockIdx.z;
  const int tid = threadIdx.x;
  const int tx = tid & 63, trow = tid >> 6;
  const int y0 = yt * 4;
  const int oc0 = og * 4;
  const int m0 = maskI[oc0], m1 = maskI[oc0 + 1], m2 = maskI[oc0 + 2], m3 = maskI[oc0 + 3];
  float* op = out + ((size_t)(n * 256 + oc0)) * 4096 + (size_t)(y0 + trow) * 64 + tx;
  if (!(m0 | m1 | m2 | m3)) {
    op[0] = 0.f; op[4096] = 0.f; op[8192] = 0.f; op[12288] = 0.f;
    return;
  }
  __shared__ float tile[6 * 66];
  const float* base = in + (size_t)n * 128 * 4096;
  const float* wb = w + (size_t)oc0 * 1152;
  float a0 = 0.f, a1 = 0.f, a2 = 0.f, a3 = 0.f;
  for (int c = 0; c < 128; c++) {
    __syncthreads();
    for (int i = tid; i < 396; i += 256) {
      int r = i / 66, col = i - r * 66;
      int yy = y0 - 1 + r, xx = col - 1;
      float v = 0.f;
      if ((unsigned)yy < 64u && (unsigned)xx < 64u) v = base[(size_t)c * 4096 + yy * 64 + xx];
      tile[i] = v;
    }
    __syncthreads();
    const int ro = trow * 66 + tx;
    float t00 = tile[ro],        t01 = tile[ro + 1],   t02 = tile[ro + 2];
    float t10 = tile[ro + 66],   t11 = tile[ro + 67],  t12 = tile[ro + 68];
    float t20 = tile[ro + 132],  t21 = tile[ro + 133], t22 = tile[ro + 134];
    const float* wc = wb + c * 9;
    if (m0) {
      const float* q = wc;
      a0 += t00*q[0] + t01*q[1] + t02*q[2] + t10*q[3] + t11*q[4] + t12*q[5] + t20*q[6] + t21*q[7] + t22*q[8];
    }
    if (m1) {
      const float* q = wc + 1152;
      a1 += t00*q[0] + t01*q[1] + t02*q[2] + t10*q[3] + t11*q[4] + t12*q[5] + t20*q[6] + t21*q[7] + t22*q[8];
    }
    if (m2) {
      const float* q = wc + 2304;
      a2 += t00*q[0] + t01*q[1] + t02*q[2] + t10*q[3] + t11*q[4] + t12*q[5] + t20*q[6] + t21*q[7] + t22*q[8];
    }
    if (m3) {
      const float* q = wc + 3456;
      a3 += t00*q[0] + t01*q[1] + t02*q[2] + t10*q[3] + t11*q[4] + t12*q[5] + t20*q[6] + t21*q[7] + t22*q[8];
    }
  }
  op[0]     = m0 ? a0 : 0.f;
  op[4096]  = m1 ? a1 : 0.f;
  op[8192]  = m2 ? a2 : 0.f;
  op[12288] = m3 ? a3 : 0.f;
}

extern "C" void kernel_launch(void* const* d_in, const int* in_sizes, int n_in,
                              void* d_out, int out_size, void* d_ws, size_t ws_size,
                              hipStream_t stream) {
  const float* in = (const float*)d_in[0];   // [16,128,64,64]
  const float* kw = (const float*)d_in[1];   // [256,128,3,3]
  const float* a  = (const float*)d_in[2];   // [1161]
  const float* b  = (const float*)d_in[3];   // [1]
  float* out = (float*)d_out;                // 16777216 + 1 + 256 floats

  char* ws = (char*)d_ws;
  float* norms2 = (float*)(ws);
  float* scale  = (float*)(ws + 1024);
  int* bucket   = (int*)(ws + 1088);
  int* count    = (int*)(ws + 2112);
  int* maskI    = (int*)(ws + 6208);

  hipMemsetAsync(count, 0, TSZ * sizeof(int), stream);
  k_sumsq<<<256, 256, 0, stream>>>(kw, norms2);
  k_scale<<<1, 256, 0, stream>>>(norms2, scale);
  k_hash<<<256, 256, 0, stream>>>(kw, a, b, scale, bucket);
  k_vote<<<256, 256, 0, stream>>>(in, a, b, count);
  k_argmax<<<1, 1024, 0, stream>>>(count, bucket, maskI, out + 16777216);

  dim3 grid(64, 16, 16);
  k_conv<<<grid, 256, 0, stream>>>(in, kw, maskI, out);
}

// Round 3
// 214.912 us; speedup vs baseline: 5.9447x; 5.9447x over previous
//
#include <hip/hip_runtime.h>
#include <cmath>
#include <cstdint>

#define TSZ 1024
#define RDIV 2.5f
#define UCONST 0.83f

typedef __bf16 bf16x8 __attribute__((ext_vector_type(8)));
typedef float f32x4 __attribute__((ext_vector_type(4)));
typedef unsigned short ushortT;

__device__ __forceinline__ ushortT bf16r(float f) {
  union { float f; unsigned u; } x; x.f = f;
  unsigned r = (x.u + 0x7FFFu + ((x.u >> 16) & 1u)) >> 16;
  return (ushortT)r;
}

__device__ __forceinline__ void glds16(const void* g, void* l) {
  __builtin_amdgcn_global_load_lds(
      (const __attribute__((address_space(1))) unsigned int*)(g),
      (__attribute__((address_space(3))) unsigned int*)(l), 16, 0, 0);
}

// ---------------- input convert: NCHW fp32 -> NHWC bf16 ----------------
__global__ __launch_bounds__(256) void k_cvt(const float* __restrict__ in,
                                             ushortT* __restrict__ nb) {
  const int bid = blockIdx.x;            // 1024 = 16 n * 64 y
  const int n = bid >> 6, y = bid & 63;
  __shared__ float tile[128][65];
  const int t = threadIdx.x;
  const int tx = t & 63, tc = t >> 6;
  for (int i = 0; i < 32; ++i) {
    int c = i * 4 + tc;
    tile[c][tx] = in[((size_t)(n * 128 + c) << 12) + (y << 6) + tx];
  }
  __syncthreads();
  const int x = t >> 2;
  ushortT* dst = nb + (((size_t)(n * 64 + y) << 6) + x) * 128;
#pragma unroll
  for (int j = 0; j < 4; ++j) {
    int c0 = (t & 3) * 8 + j * 32;
    union { ushortT us[8]; uint4 v; } pk;
#pragma unroll
    for (int u = 0; u < 8; ++u) pk.us[u] = bf16r(tile[c0 + u][x]);
    *reinterpret_cast<uint4*>(dst + c0) = pk.v;
  }
}

// ---------------- hash pipeline (fp32-exact) ----------------
__global__ __launch_bounds__(256) void k_sumsq(const float* __restrict__ k,
                                               float* __restrict__ norms2) {
  int o = blockIdx.x;
  const float* row = k + (size_t)o * 1152;
  float s = 0.f;
  for (int j = threadIdx.x; j < 1152; j += 256) { float v = row[j]; s += v * v; }
  __shared__ float red[256];
  red[threadIdx.x] = s; __syncthreads();
  for (int st = 128; st; st >>= 1) {
    if (threadIdx.x < st) red[threadIdx.x] += red[threadIdx.x + st];
    __syncthreads();
  }
  if (threadIdx.x == 0) norms2[o] = red[0];
}

__global__ __launch_bounds__(256) void k_scale(const float* __restrict__ norms2,
                                               float* __restrict__ scale) {
  __shared__ float red[256];
  red[threadIdx.x] = norms2[threadIdx.x]; __syncthreads();
  for (int st = 128; st; st >>= 1) {
    if (threadIdx.x < st) red[threadIdx.x] = fmaxf(red[threadIdx.x], red[threadIdx.x + st]);
    __syncthreads();
  }
  if (threadIdx.x == 0) scale[0] = UCONST / sqrtf(red[0]);
}

__global__ __launch_bounds__(256) void k_hash(const float* __restrict__ k,
                                              const float* __restrict__ a,
                                              const float* __restrict__ b,
                                              const float* __restrict__ scalep,
                                              int* __restrict__ bucket) {
  int o = blockIdx.x;
  float scale = scalep[0];
  const float* row = k + (size_t)o * 1152;
  float dot = 0.f, p = 0.f;
  for (int j = threadIdx.x; j < 1152; j += 256) {
    float x = row[j] * scale;
    dot += x * a[j];
    p += x * x;
  }
  __shared__ float rd[256], rp[256];
  rd[threadIdx.x] = dot; rp[threadIdx.x] = p; __syncthreads();
  for (int st = 128; st; st >>= 1) {
    if (threadIdx.x < st) { rd[threadIdx.x] += rd[threadIdx.x + st]; rp[threadIdx.x] += rp[threadIdx.x + st]; }
    __syncthreads();
  }
  if (threadIdx.x == 0) {
    float acc = rd[0];
    float pw = rp[0];
    for (int i = 0; i < 9; i++) { acc += pw * a[1152 + i]; pw = pw * pw; }
    acc += b[0];
    float h = floorf(acc / RDIV);
    int hi = (int)h;
    int r = hi % TSZ; if (r < 0) r = -r;
    bucket[o] = r;
  }
}

// ---------------- vote: LDS-staged fp32 conv with hash vector ----------------
__global__ __launch_bounds__(256) void k_vote2(const float* __restrict__ in,
                                               const float* __restrict__ a,
                                               const float* __restrict__ bb,
                                               int* __restrict__ count) {
  __shared__ float sb[6][8][64];   // rows y0-1..y0+4, 8 channels, 64 x
  __shared__ int hist[TSZ];
  const int t = threadIdx.x;
  for (int i = t; i < TSZ; i += 256) hist[i] = 0;
  const int bid = blockIdx.x;          // 256 = 16 n * 16 stripes
  const int n = bid >> 4, y0 = (bid & 15) << 2;
  const int x = t & 63, ry = t >> 6;   // pixel (y0+ry, x)
  const int yq = y0 + ry;
  float acc = 0.f;
  const float* base = in + (size_t)n * 524288;
  for (int cc = 0; cc < 16; ++cc) {
    __syncthreads();
#pragma unroll
    for (int k = 0; k < 12; ++k) {
      int i = k * 256 + t;
      int row = i >> 9;
      int c8 = (i >> 6) & 7;
      int xx = i & 63;
      int yy = y0 - 1 + row;
      float v = 0.f;
      if ((unsigned)yy < 64u) v = base[(size_t)(cc * 8 + c8) * 4096 + yy * 64 + xx];
      sb[row][c8][xx] = v;
    }
    __syncthreads();
#pragma unroll
    for (int c8 = 0; c8 < 8; ++c8) {
      const float* av = a + (cc * 8 + c8) * 9;
#pragma unroll
      for (int ky = 0; ky < 3; ++ky) {
        const float* rowp = sb[ry + ky][c8];
        float left  = (x >= 1)  ? rowp[x - 1] : 0.f;
        float mid   = rowp[x];
        float right = (x <= 62) ? rowp[x + 1] : 0.f;
        acc += left * av[ky * 3 + 0] + mid * av[ky * 3 + 1] + right * av[ky * 3 + 2];
      }
    }
  }
  {
    const float* av = a + 1152;
#pragma unroll
    for (int ky = 0; ky < 3; ++ky) {
      int yy = yq + ky - 1;
      if ((unsigned)yy >= 64u) continue;
#pragma unroll
      for (int kx = 0; kx < 3; ++kx) {
        int xx = x + kx - 1;
        if ((unsigned)xx >= 64u) continue;
        acc += 0.5f * av[ky * 3 + kx];
      }
    }
  }
  int v = (int)floorf((acc + bb[0]) / RDIV);
  int r = v % TSZ; if (r < 0) r = -r;
  atomicAdd(&hist[r], 1);
  __syncthreads();
  for (int i = t; i < TSZ; i += 256) {
    int h = hist[i];
    if (h) atomicAdd(&count[i], h);
  }
}

__global__ __launch_bounds__(1024) void k_argmax(const int* __restrict__ count,
                                                 const int* __restrict__ bucket,
                                                 int* __restrict__ maskI,
                                                 float* __restrict__ tail) {
  __shared__ int sc[1024];
  __shared__ int si[1024];
  int t = threadIdx.x;
  sc[t] = count[t]; si[t] = t; __syncthreads();
  for (int st = 512; st; st >>= 1) {
    if (t < st) {
      int c2 = sc[t + st], i2 = si[t + st];
      if (c2 > sc[t] || (c2 == sc[t] && i2 < si[t])) { sc[t] = c2; si[t] = i2; }
    }
    __syncthreads();
  }
  int idx = si[0];
  if (t == 0) tail[0] = (float)idx;
  if (t < 256) {
    int m = (bucket[t] == idx) ? 1 : 0;
    maskI[t] = m;
    tail[1 + t] = (float)m;
  }
}

// ---------------- weight prep: masked bf16, k = tap*128 + c ----------------
__global__ __launch_bounds__(256) void k_wprep(const float* __restrict__ w,
                                               const int* __restrict__ maskI,
                                               ushortT* __restrict__ wb) {
  const int o = blockIdx.x;
  const float m = maskI[o] ? 1.f : 0.f;
  const float* wr = w + (size_t)o * 1152;
  ushortT* dst = wb + (size_t)o * 1152;
  for (int j = threadIdx.x; j < 1152; j += 256) {
    int r = j >> 7, c = j & 127;
    dst[j] = bf16r(wr[c * 9 + r] * m);
  }
}

// ---------------- implicit-GEMM conv: M=65536, N=256, K=1152 ----------------
// BM=128 (2 rows), BN=128, BK=32; 4 waves as 2x2, each 64x64; 36 K-steps.
__global__ __launch_bounds__(256) void k_gemm(const ushortT* __restrict__ nb,
                                              const ushortT* __restrict__ wb,
                                              const char* __restrict__ zpage,
                                              float* __restrict__ out) {
  __shared__ __align__(16) ushortT As[2][4096];
  __shared__ __align__(16) ushortT Bs[2][4096];
  const int t = threadIdx.x, l = t & 63, w = t >> 6;
  const int mb = blockIdx.x, ob = blockIdx.y;
  const int n = mb >> 5;
  const int y0 = (mb * 2) & 63;
  const int o0 = ob * 128;
  const int wm = w & 1, wn = w >> 1;
  const int lq = l >> 2, lc = l & 3;

  const char* baseA[2];
  const char* baseB[2];
  int yabsq[2], xqv[2];
#pragma unroll
  for (int q = 0; q < 2; ++q) {
    int mq = w * 32 + q * 16 + lq;            // 0..127
    int yl = mq >> 6, xq = mq & 63;
    yabsq[q] = y0 + yl;
    xqv[q] = xq;
    baseA[q] = (const char*)nb + ((size_t)(n * 4096 + yabsq[q] * 64 + xq)) * 256 + lc * 16;
    int oq = o0 + w * 32 + q * 16 + lq;
    baseB[q] = (const char*)wb + (size_t)oq * 2304 + lc * 16;
  }

  constexpr int DY[9] = {-1,-1,-1, 0,0,0, 1,1,1};
  constexpr int DX[9] = {-1, 0, 1,-1,0,1,-1,0,1};

  auto stage = [&](int dst, int s1) {
    const int r = s1 >> 2, cc = s1 & 3;
    const int dy = DY[r], dx = DX[r];
    const int offA = (dy * 64 + dx) * 256 + cc * 64;
#pragma unroll
    for (int q = 0; q < 2; ++q) {
      bool val = ((unsigned)(yabsq[q] + dy) < 64u) && ((unsigned)(xqv[q] + dx) < 64u);
      const char* sa = val ? (baseA[q] + offA) : (zpage + lc * 16);
      glds16(sa, (char*)(&As[dst][0]) + (w * 2 + q) * 1024);
      glds16(baseB[q] + s1 * 64, (char*)(&Bs[dst][0]) + (w * 2 + q) * 1024);
    }
  };

  f32x4 acc[4][4] = {};

  stage(0, 0);
  __syncthreads();

  const int lr = l & 15, lk = l >> 4;
#pragma unroll
  for (int s = 0; s < 36; ++s) {
    const int cur = s & 1;
    if (s < 35) stage(cur ^ 1, s + 1);
    const ushortT* ap = &As[cur][(wm * 64 + lr) * 32 + lk * 8];
    const ushortT* bp = &Bs[cur][(wn * 64 + lr) * 32 + lk * 8];
    bf16x8 af[4], bfr[4];
#pragma unroll
    for (int i = 0; i < 4; ++i) {
      af[i]  = *reinterpret_cast<const bf16x8*>(ap + i * 512);
      bfr[i] = *reinterpret_cast<const bf16x8*>(bp + i * 512);
    }
#pragma unroll
    for (int mi = 0; mi < 4; ++mi)
#pragma unroll
      for (int ni = 0; ni < 4; ++ni)
        acc[mi][ni] = __builtin_amdgcn_mfma_f32_16x16x32_bf16(af[mi], bfr[ni], acc[mi][ni], 0, 0, 0);
    __syncthreads();
  }

  const int pos0 = (mb & 31) * 128;
#pragma unroll
  for (int ni = 0; ni < 4; ++ni) {
    const int o = o0 + wn * 64 + ni * 16 + (l & 15);
    float* op = out + (((size_t)(n * 256 + o)) << 12) + pos0 + wm * 64 + (l >> 4) * 4;
#pragma unroll
    for (int mi = 0; mi < 4; ++mi)
      *reinterpret_cast<f32x4*>(op + mi * 16) = acc[mi][ni];
  }
}

// ---------------- fallback direct conv (round-1, known-good) ----------------
__global__ __launch_bounds__(256) void k_conv(const float* __restrict__ in,
                                              const float* __restrict__ w,
                                              const int* __restrict__ maskI,
                                              float* __restrict__ out) {
  const int og = blockIdx.x, n = blockIdx.y, yt = blockIdx.z;
  const int tid = threadIdx.x;
  const int tx = tid & 63, trow = tid >> 6;
  const int y0 = yt * 4;
  const int oc0 = og * 4;
  const int m0 = maskI[oc0], m1 = maskI[oc0 + 1], m2 = maskI[oc0 + 2], m3 = maskI[oc0 + 3];
  float* op = out + ((size_t)(n * 256 + oc0)) * 4096 + (size_t)(y0 + trow) * 64 + tx;
  if (!(m0 | m1 | m2 | m3)) {
    op[0] = 0.f; op[4096] = 0.f; op[8192] = 0.f; op[12288] = 0.f;
    return;
  }
  __shared__ float tile[6 * 66];
  const float* base = in + (size_t)n * 128 * 4096;
  const float* wb = w + (size_t)oc0 * 1152;
  float a0 = 0.f, a1 = 0.f, a2 = 0.f, a3 = 0.f;
  for (int c = 0; c < 128; c++) {
    __syncthreads();
    for (int i = tid; i < 396; i += 256) {
      int r = i / 66, col = i - r * 66;
      int yy = y0 - 1 + r, xx = col - 1;
      float v = 0.f;
      if ((unsigned)yy < 64u && (unsigned)xx < 64u) v = base[(size_t)c * 4096 + yy * 64 + xx];
      tile[i] = v;
    }
    __syncthreads();
    const int ro = trow * 66 + tx;
    float t00 = tile[ro],        t01 = tile[ro + 1],   t02 = tile[ro + 2];
    float t10 = tile[ro + 66],   t11 = tile[ro + 67],  t12 = tile[ro + 68];
    float t20 = tile[ro + 132],  t21 = tile[ro + 133], t22 = tile[ro + 134];
    const float* wc = wb + c * 9;
    if (m0) {
      const float* q = wc;
      a0 += t00*q[0] + t01*q[1] + t02*q[2] + t10*q[3] + t11*q[4] + t12*q[5] + t20*q[6] + t21*q[7] + t22*q[8];
    }
    if (m1) {
      const float* q = wc + 1152;
      a1 += t00*q[0] + t01*q[1] + t02*q[2] + t10*q[3] + t11*q[4] + t12*q[5] + t20*q[6] + t21*q[7] + t22*q[8];
    }
    if (m2) {
      const float* q = wc + 2304;
      a2 += t00*q[0] + t01*q[1] + t02*q[2] + t10*q[3] + t11*q[4] + t12*q[5] + t20*q[6] + t21*q[7] + t22*q[8];
    }
    if (m3) {
      const float* q = wc + 3456;
      a3 += t00*q[0] + t01*q[1] + t02*q[2] + t10*q[3] + t11*q[4] + t12*q[5] + t20*q[6] + t21*q[7] + t22*q[8];
    }
  }
  op[0]     = m0 ? a0 : 0.f;
  op[4096]  = m1 ? a1 : 0.f;
  op[8192]  = m2 ? a2 : 0.f;
  op[12288] = m3 ? a3 : 0.f;
}

extern "C" void kernel_launch(void* const* d_in, const int* in_sizes, int n_in,
                              void* d_out, int out_size, void* d_ws, size_t ws_size,
                              hipStream_t stream) {
  const float* in = (const float*)d_in[0];   // [16,128,64,64]
  const float* kw = (const float*)d_in[1];   // [256,128,3,3]
  const float* a  = (const float*)d_in[2];   // [1161]
  const float* b  = (const float*)d_in[3];   // [1]
  float* out = (float*)d_out;                // 16777216 + 1 + 256 floats

  char* ws = (char*)d_ws;
  const size_t NEED = 17374720ULL;           // nb(16MB) + wb + small + zpage

  if (ws_size >= NEED) {
    // -------- fast path: bf16 MFMA implicit GEMM --------
    ushortT* nb   = (ushortT*)(ws);                    // 16,777,216 B NHWC bf16
    ushortT* wb   = (ushortT*)(ws + 16777216);         // 589,824 B
    float* norms2 = (float*)(ws + 17367040);
    float* scale  = (float*)(ws + 17368064);
    int* bucket   = (int*)(ws + 17368320);
    int* count    = (int*)(ws + 17369344);
    int* maskI    = (int*)(ws + 17373440);
    char* zpage   = (ws + 17374464);                   // 256 B zeros

    hipMemsetAsync(count, 0, TSZ * sizeof(int), stream);
    hipMemsetAsync(zpage, 0, 256, stream);

    k_cvt<<<1024, 256, 0, stream>>>(in, nb);
    k_sumsq<<<256, 256, 0, stream>>>(kw, norms2);
    k_scale<<<1, 256, 0, stream>>>(norms2, scale);
    k_hash<<<256, 256, 0, stream>>>(kw, a, b, scale, bucket);
    k_vote2<<<256, 256, 0, stream>>>(in, a, b, count);
    k_argmax<<<1, 1024, 0, stream>>>(count, bucket, maskI, out + 16777216);
    k_wprep<<<256, 256, 0, stream>>>(kw, maskI, wb);

    dim3 grid(512, 2);
    k_gemm<<<grid, 256, 0, stream>>>(nb, wb, zpage, out);
  } else {
    // -------- fallback: round-1 direct conv (known-good) --------
    float* norms2 = (float*)(ws);
    float* scale  = (float*)(ws + 1024);
    int* bucket   = (int*)(ws + 1088);
    int* count    = (int*)(ws + 2112);
    int* maskI    = (int*)(ws + 6208);

    hipMemsetAsync(count, 0, TSZ * sizeof(int), stream);
    k_sumsq<<<256, 256, 0, stream>>>(kw, norms2);
    k_scale<<<1, 256, 0, stream>>>(norms2, scale);
    k_hash<<<256, 256, 0, stream>>>(kw, a, b, scale, bucket);
    k_vote2<<<256, 256, 0, stream>>>(in, a, b, count);
    k_argmax<<<1, 1024, 0, stream>>>(count, bucket, maskI, out + 16777216);

    dim3 grid(64, 16, 16);
    k_conv<<<grid, 256, 0, stream>>>(in, kw, maskI, out);
  }
}